// Round 6
// baseline (708.573 us; speedup 1.0000x reference)
//
#include <hip/hip_runtime.h>

#define N_NODES 50000
#define N_EDGES 600000
#define HID 128
#define N_LAYERS 5
#define SCAN_BLK 256
#define N_SCAN_BLOCKS ((N_NODES + SCAN_BLK - 1) / SCAN_BLK)   // 196
#define NH ((size_t)N_NODES * HID)
#define NSLICE 8
#define SL_STRIDE ((size_t)N_NODES * 16)   // u32 per slice

typedef unsigned int u32;
typedef _Float16 half8 __attribute__((ext_vector_type(8)));
typedef _Float16 half4 __attribute__((ext_vector_type(4)));
typedef float f32x4 __attribute__((ext_vector_type(4)));
typedef u32 u32x8 __attribute__((ext_vector_type(8)));

// packed split format: one u32 per feature; h[0]=fp16 hi, h[1]=fp16 residual
union PK { u32 u; _Float16 h[2]; };

__device__ inline u32 pack_split(float v) {
    PK r;
    r.h[0] = (_Float16)v;
    r.h[1] = (_Float16)(v - (float)r.h[0]);
    return r.u;
}
__device__ inline float unpack_sum(u32 p) {
    PK r; r.u = p;
    return (float)r.h[0] + (float)r.h[1];
}

// ---------------- CSR build ----------------

__global__ void deg_count(const int* __restrict__ dst, int* __restrict__ deg) {
    int e = blockIdx.x * blockDim.x + threadIdx.x;
    if (e < N_EDGES) atomicAdd(&deg[dst[e]], 1);
}

__global__ __launch_bounds__(SCAN_BLK) void deg_reduce(const int* __restrict__ deg,
                                                       int* __restrict__ block_sums) {
    __shared__ int s[SCAN_BLK];
    int i = blockIdx.x * SCAN_BLK + threadIdx.x;
    int v = (i < N_NODES) ? deg[i] : 0;
    s[threadIdx.x] = v;
    __syncthreads();
    for (int off = SCAN_BLK / 2; off > 0; off >>= 1) {
        if (threadIdx.x < off) s[threadIdx.x] += s[threadIdx.x + off];
        __syncthreads();
    }
    if (threadIdx.x == 0) block_sums[blockIdx.x] = s[0];
}

__global__ __launch_bounds__(SCAN_BLK) void scan_partials(const int* __restrict__ block_sums,
                                                          int* __restrict__ block_off) {
    __shared__ int s[SCAN_BLK];
    int t = threadIdx.x;
    int v = (t < N_SCAN_BLOCKS) ? block_sums[t] : 0;
    s[t] = v;
    __syncthreads();
    for (int off = 1; off < SCAN_BLK; off <<= 1) {
        int u = (t >= off) ? s[t - off] : 0;
        __syncthreads();
        s[t] += u;
        __syncthreads();
    }
    if (t < N_SCAN_BLOCKS) block_off[t] = s[t] - v;
}

__global__ __launch_bounds__(SCAN_BLK) void scan_write(const int* __restrict__ deg,
        const int* __restrict__ block_off, int* __restrict__ row_ptr,
        int* __restrict__ cursor, float* __restrict__ deg_inv) {
    __shared__ int s[SCAN_BLK];
    int t = threadIdx.x;
    int i = blockIdx.x * SCAN_BLK + t;
    int v = (i < N_NODES) ? deg[i] : 0;
    s[t] = v;
    __syncthreads();
    for (int off = 1; off < SCAN_BLK; off <<= 1) {
        int u = (t >= off) ? s[t - off] : 0;
        __syncthreads();
        s[t] += u;
        __syncthreads();
    }
    int excl = s[t] - v + block_off[blockIdx.x];
    if (i < N_NODES) {
        row_ptr[i] = excl;
        cursor[i]  = excl;
        deg_inv[i] = 1.0f / (float)max(v, 1);
    }
    if (i == N_NODES) row_ptr[N_NODES] = excl;
}

__global__ void fill_csr(const int* __restrict__ src, const int* __restrict__ dst,
                         int* __restrict__ cursor, int* __restrict__ col) {
    int e = blockIdx.x * blockDim.x + threadIdx.x;
    if (e < N_EDGES) {
        int d = dst[e];
        int pos = atomicAdd(&cursor[d], 1);
        col[pos] = src[e];
    }
}

// ---------------- splits ----------------

__global__ void split_sep(const float* __restrict__ src,
                          _Float16* __restrict__ hi, _Float16* __restrict__ lo, int n4) {
    int i = blockIdx.x * blockDim.x + threadIdx.x;
    if (i >= n4) return;
    float4 v = *(const float4*)(src + (size_t)i * 4);
    half4 h, l;
    h.x = (_Float16)v.x; l.x = (_Float16)(v.x - (float)h.x);
    h.y = (_Float16)v.y; l.y = (_Float16)(v.y - (float)h.y);
    h.z = (_Float16)v.z; l.z = (_Float16)(v.z - (float)h.z);
    h.w = (_Float16)v.w; l.w = (_Float16)(v.w - (float)h.w);
    *(half4*)(hi + (size_t)i * 4) = h;
    *(half4*)(lo + (size_t)i * 4) = l;
}

// features: packed u32, SLICE-MAJOR layout [slice][node][16]
__global__ void split_pk_sl(const float* __restrict__ src, u32* __restrict__ dst, int nq) {
    int i = blockIdx.x * blockDim.x + threadIdx.x;   // quad index
    if (i >= nq) return;
    int n = i >> 5;          // node
    int c = i & 31;          // quad within row (4 features)
    float4 v = *(const float4*)(src + (size_t)n * HID + c * 4);
    uint4 r;
    r.x = pack_split(v.x); r.y = pack_split(v.y);
    r.z = pack_split(v.z); r.w = pack_split(v.w);
    int slice = c >> 2, rem = (c & 3) * 4;
    *(uint4*)(dst + (size_t)slice * SL_STRIDE + (size_t)n * 16 + rem) = r;
}

// ---- slice-major mean aggregation ----
// block: 4 waves, one (slice, 4-node group). slice = blockIdx&7 -> XCD pinning
// (round-robin dispatch): each XCD's L2 caches one 3.2MB slice of the table.
// wave: 16 edge-slots x 4 lanes; lane loads uint4 (4 features of one neighbor).

__global__ __launch_bounds__(256) void aggregate_sl(const u32* __restrict__ hp,
        const int* __restrict__ row_ptr, const int* __restrict__ col,
        const float* __restrict__ deg_inv, u32* __restrict__ mp) {
    const int wave  = threadIdx.x >> 6;
    const int lane  = threadIdx.x & 63;
    const int slice = blockIdx.x & 7;
    const int node  = (blockIdx.x >> 3) * 4 + wave;
    if (node >= N_NODES) return;
    const u32* hsl = hp + (size_t)slice * SL_STRIDE;
    int beg = row_ptr[node], end = row_ptr[node + 1];
    int deg = end - beg;
    const int eslot = lane >> 2;         // 0..15
    const int rem   = (lane & 3) * 4;    // u32 offset within slice
    float a0 = 0.f, a1 = 0.f, a2 = 0.f, a3 = 0.f;

    for (int base = 0; base < deg; base += 16) {
        int cnt = deg - base; if (cnt > 16) cnt = 16;
        int p = beg + base + (lane & 15);
        int ci = col[(p < end) ? p : (end - 1)];   // coalesced id chunk
        int srcn = __shfl(ci, eslot, 64);
        if (eslot < cnt) {
            uint4 v = *(const uint4*)(hsl + (size_t)srcn * 16 + rem);
            a0 += unpack_sum(v.x); a1 += unpack_sum(v.y);
            a2 += unpack_sum(v.z); a3 += unpack_sum(v.w);
        }
    }
    // reduce across the 16 edge-slots (lanes sharing lane&3)
    a0 += __shfl_xor(a0, 4, 64);  a1 += __shfl_xor(a1, 4, 64);
    a2 += __shfl_xor(a2, 4, 64);  a3 += __shfl_xor(a3, 4, 64);
    a0 += __shfl_xor(a0, 8, 64);  a1 += __shfl_xor(a1, 8, 64);
    a2 += __shfl_xor(a2, 8, 64);  a3 += __shfl_xor(a3, 8, 64);
    a0 += __shfl_xor(a0, 16, 64); a1 += __shfl_xor(a1, 16, 64);
    a2 += __shfl_xor(a2, 16, 64); a3 += __shfl_xor(a3, 16, 64);
    a0 += __shfl_xor(a0, 32, 64); a1 += __shfl_xor(a1, 32, 64);
    a2 += __shfl_xor(a2, 32, 64); a3 += __shfl_xor(a3, 32, 64);
    if (lane < 4) {
        float di = deg_inv[node];
        uint4 r;
        r.x = pack_split(a0 * di);
        r.y = pack_split(a1 * di);
        r.z = pack_split(a2 * di);
        r.w = pack_split(a3 * di);
        *(uint4*)(mp + (size_t)slice * SL_STRIDE + (size_t)node * 16 + rem) = r;
    }
}

// ---------------- MFMA GEMM, slice-major A, two-phase hi/lo weight staging ------
// 512 thr = 8 waves x 16 rows = 128 rows/block, 391 blocks.
// LDS 64KB (2 matrices) -> 2 blocks/CU, ~4 waves/SIMD.

__device__ inline void unpk8(u32x8 p, half8& hi, half8& lo) {
    #pragma unroll
    for (int i = 0; i < 8; ++i) {
        PK t; t.u = p[i];
        hi[i] = t.h[0];
        lo[i] = t.h[1];
    }
}
__device__ inline void unpk8_hi(u32x8 p, half8& hi) {
    #pragma unroll
    for (int i = 0; i < 8; ++i) {
        PK t; t.u = p[i];
        hi[i] = t.h[0];
    }
}

__global__ __launch_bounds__(512, 4) void gemm_mfma(
        const u32* __restrict__ mean_pk, const u32* __restrict__ h_pk,
        const _Float16* __restrict__ Wlh, const _Float16* __restrict__ Wll,
        const _Float16* __restrict__ Wrh, const _Float16* __restrict__ Wrl,
        const float* __restrict__ bias,
        u32* __restrict__ out_pk, float* __restrict__ out_f32, int final_layer) {
    __shared__ char Wlds[65536];           // 2 mats x [128 j][128 k] fp16, swizzled
    const int t    = threadIdx.x;
    const int lane = t & 63;
    const int w    = t >> 6;
    const int jr   = lane & 15;
    const int q    = lane >> 4;

    const int basew = blockIdx.x * 128 + w * 16;
    int r0 = basew + jr; if (r0 > N_NODES - 1) r0 = N_NODES - 1;

    f32x4 accL[8], accR[8];
    #pragma unroll
    for (int jt = 0; jt < 8; ++jt) { accL[jt] = (f32x4)(0.f); accR[jt] = (f32x4)(0.f); }

    // ---- phase A: hi weights (Wlh, Wrh) ----
    #pragma unroll
    for (int i = 0; i < 4; ++i) {
        int gi = t + i * 512;
        int j = gi >> 4, p = gi & 15;
        int dstb = j * 256 + ((p ^ (j & 7)) * 16);
        int srci = j * HID + p * 8;
        *(half8*)&Wlds[dstb]         = *(const half8*)(Wlh + srci);
        *(half8*)&Wlds[32768 + dstb] = *(const half8*)(Wrh + srci);
    }
    __syncthreads();
    #pragma unroll 2
    for (int kk = 0; kk < 4; ++kk) {
        size_t a = ((size_t)(2 * kk + (q >> 1)) * N_NODES + r0) * 16 + (q & 1) * 8;
        u32x8 mp8 = *(const u32x8*)(mean_pk + a);
        u32x8 hp8 = *(const u32x8*)(h_pk + a);
        half8 mh, ml, hh, hl;
        unpk8(mp8, mh, ml); unpk8(hp8, hh, hl);
        #pragma unroll
        for (int jt = 0; jt < 8; ++jt) {
            int j  = jt * 16 + jr;
            int wb = j * 256 + (((kk * 4 + q) ^ (j & 7)) * 16);
            half8 wl = *(const half8*)&Wlds[wb];
            half8 wr = *(const half8*)&Wlds[32768 + wb];
            accL[jt] = __builtin_amdgcn_mfma_f32_16x16x32_f16(mh, wl, accL[jt], 0, 0, 0);
            accL[jt] = __builtin_amdgcn_mfma_f32_16x16x32_f16(ml, wl, accL[jt], 0, 0, 0);
            accR[jt] = __builtin_amdgcn_mfma_f32_16x16x32_f16(hh, wr, accR[jt], 0, 0, 0);
            accR[jt] = __builtin_amdgcn_mfma_f32_16x16x32_f16(hl, wr, accR[jt], 0, 0, 0);
        }
    }
    __syncthreads();

    // ---- phase B: lo weights (Wll, Wrl), hi A only ----
    #pragma unroll
    for (int i = 0; i < 4; ++i) {
        int gi = t + i * 512;
        int j = gi >> 4, p = gi & 15;
        int dstb = j * 256 + ((p ^ (j & 7)) * 16);
        int srci = j * HID + p * 8;
        *(half8*)&Wlds[dstb]         = *(const half8*)(Wll + srci);
        *(half8*)&Wlds[32768 + dstb] = *(const half8*)(Wrl + srci);
    }
    __syncthreads();
    #pragma unroll 2
    for (int kk = 0; kk < 4; ++kk) {
        size_t a = ((size_t)(2 * kk + (q >> 1)) * N_NODES + r0) * 16 + (q & 1) * 8;
        u32x8 mp8 = *(const u32x8*)(mean_pk + a);
        u32x8 hp8 = *(const u32x8*)(h_pk + a);
        half8 mh, hh;
        unpk8_hi(mp8, mh); unpk8_hi(hp8, hh);
        #pragma unroll
        for (int jt = 0; jt < 8; ++jt) {
            int j  = jt * 16 + jr;
            int wb = j * 256 + (((kk * 4 + q) ^ (j & 7)) * 16);
            half8 wl = *(const half8*)&Wlds[wb];
            half8 wr = *(const half8*)&Wlds[32768 + wb];
            accL[jt] = __builtin_amdgcn_mfma_f32_16x16x32_f16(mh, wl, accL[jt], 0, 0, 0);
            accR[jt] = __builtin_amdgcn_mfma_f32_16x16x32_f16(hh, wr, accR[jt], 0, 0, 0);
        }
    }

    // ---- epilogue: C/D row=(lane>>4)*4+g, col=lane&15 ----
    float bv[8];
    #pragma unroll
    for (int jt = 0; jt < 8; ++jt) bv[jt] = bias[jt * 16 + jr];

    #pragma unroll
    for (int jt = 0; jt < 8; ++jt) {
        #pragma unroll
        for (int g = 0; g < 4; ++g) {
            int row = basew + q * 4 + g;
            if (row < N_NODES) {
                float v = accL[jt][g] + accR[jt][g] + bv[jt];
                if (final_layer) {
                    out_f32[(size_t)row * HID + jt * 16 + jr] = v;
                } else {
                    out_pk[((size_t)jt * N_NODES + row) * 16 + jr] =
                        pack_split(fmaxf(v, 0.f));
                }
            }
        }
    }
}

// ---------------- launch ----------------

extern "C" void kernel_launch(void* const* d_in, const int* in_sizes, int n_in,
                              void* d_out, int out_size, void* d_ws, size_t ws_size,
                              hipStream_t stream) {
    const float* x    = (const float*)d_in[0];
    const int*   edge = (const int*)d_in[1];
    const float* Wl   = (const float*)d_in[2];
    const float* Wr   = (const float*)d_in[3];
    const float* bias = (const float*)d_in[4];
    float* out = (float*)d_out;

    u32* h_pk    = (u32*)d_ws;                    // 25.6 MB, slice-major
    u32* mean_pk = h_pk + NH;                     // 25.6 MB, slice-major
    _Float16* Wlh = (_Float16*)(mean_pk + NH);
    _Float16* Wll = Wlh + 81920;
    _Float16* Wrh = Wll + 81920;
    _Float16* Wrl = Wrh + 81920;
    float* deg_inv = (float*)(Wrl + 81920);
    int*   deg     = (int*)(deg_inv + N_NODES);
    int*   row_ptr = deg + N_NODES;
    int*   cursor  = row_ptr + (N_NODES + 1);
    int*   colarr  = cursor + N_NODES;
    int*   blk_sums = colarr + N_EDGES;
    int*   blk_off  = blk_sums + N_SCAN_BLOCKS;

    const int* src = edge;
    const int* dst = edge + N_EDGES;

    hipMemsetAsync(deg, 0, N_NODES * sizeof(int), stream);
    deg_count<<<(N_EDGES + 255) / 256, 256, 0, stream>>>(dst, deg);
    deg_reduce<<<N_SCAN_BLOCKS, SCAN_BLK, 0, stream>>>(deg, blk_sums);
    scan_partials<<<1, SCAN_BLK, 0, stream>>>(blk_sums, blk_off);
    scan_write<<<N_SCAN_BLOCKS, SCAN_BLK, 0, stream>>>(deg, blk_off, row_ptr,
                                                       cursor, deg_inv);
    fill_csr<<<(N_EDGES + 255) / 256, 256, 0, stream>>>(src, dst, cursor, colarr);

    split_sep<<<(20480 + 255) / 256, 256, 0, stream>>>(Wl, Wlh, Wll, 20480);
    split_sep<<<(20480 + 255) / 256, 256, 0, stream>>>(Wr, Wrh, Wrl, 20480);
    split_pk_sl<<<(1600000 + 255) / 256, 256, 0, stream>>>(x, h_pk, 1600000);

    const int agg_blocks = ((N_NODES + 3) / 4) * NSLICE;   // 100000
    const int gemm_blocks = (N_NODES + 127) / 128;         // 391

    for (int l = 0; l < N_LAYERS; ++l) {
        aggregate_sl<<<agg_blocks, 256, 0, stream>>>(
            h_pk, row_ptr, colarr, deg_inv, mean_pk);
        gemm_mfma<<<gemm_blocks, 512, 0, stream>>>(
            mean_pk, h_pk,
            Wlh + (size_t)l * 16384, Wll + (size_t)l * 16384,
            Wrh + (size_t)l * 16384, Wrl + (size_t)l * 16384,
            bias + (size_t)l * HID,
            h_pk, out, (l == N_LAYERS - 1) ? 1 : 0);
    }
}

// Round 7
// 534.486 us; speedup vs baseline: 1.3257x; 1.3257x over previous
//
#include <hip/hip_runtime.h>

#define N_NODES 50000
#define N_EDGES 600000
#define HID 128
#define N_LAYERS 5
#define SCAN_BLK 256
#define N_SCAN_BLOCKS ((N_NODES + SCAN_BLK - 1) / SCAN_BLK)   // 196
#define NH ((size_t)N_NODES * HID)
#define NSLICE 8
#define SL_STRIDE ((size_t)N_NODES * 16)   // u32 per slice

typedef unsigned int u32;
typedef _Float16 half8 __attribute__((ext_vector_type(8)));
typedef _Float16 half4 __attribute__((ext_vector_type(4)));
typedef float f32x4 __attribute__((ext_vector_type(4)));
typedef u32 u32x8 __attribute__((ext_vector_type(8)));

// packed split format: one u32 per feature; h[0]=fp16 hi, h[1]=fp16 residual
union PK { u32 u; _Float16 h[2]; };

__device__ inline u32 pack_split(float v) {
    PK r;
    r.h[0] = (_Float16)v;
    r.h[1] = (_Float16)(v - (float)r.h[0]);
    return r.u;
}
__device__ inline float unpack_sum(u32 p) {
    PK r; r.u = p;
    return (float)r.h[0] + (float)r.h[1];
}

// ---------------- CSR build ----------------

__global__ void deg_count(const int* __restrict__ dst, int* __restrict__ deg) {
    int e = blockIdx.x * blockDim.x + threadIdx.x;
    if (e < N_EDGES) atomicAdd(&deg[dst[e]], 1);
}

__global__ __launch_bounds__(SCAN_BLK) void deg_reduce(const int* __restrict__ deg,
                                                       int* __restrict__ block_sums) {
    __shared__ int s[SCAN_BLK];
    int i = blockIdx.x * SCAN_BLK + threadIdx.x;
    int v = (i < N_NODES) ? deg[i] : 0;
    s[threadIdx.x] = v;
    __syncthreads();
    for (int off = SCAN_BLK / 2; off > 0; off >>= 1) {
        if (threadIdx.x < off) s[threadIdx.x] += s[threadIdx.x + off];
        __syncthreads();
    }
    if (threadIdx.x == 0) block_sums[blockIdx.x] = s[0];
}

__global__ __launch_bounds__(SCAN_BLK) void scan_partials(const int* __restrict__ block_sums,
                                                          int* __restrict__ block_off) {
    __shared__ int s[SCAN_BLK];
    int t = threadIdx.x;
    int v = (t < N_SCAN_BLOCKS) ? block_sums[t] : 0;
    s[t] = v;
    __syncthreads();
    for (int off = 1; off < SCAN_BLK; off <<= 1) {
        int u = (t >= off) ? s[t - off] : 0;
        __syncthreads();
        s[t] += u;
        __syncthreads();
    }
    if (t < N_SCAN_BLOCKS) block_off[t] = s[t] - v;
}

__global__ __launch_bounds__(SCAN_BLK) void scan_write(const int* __restrict__ deg,
        const int* __restrict__ block_off, int* __restrict__ row_ptr,
        int* __restrict__ cursor, float* __restrict__ deg_inv) {
    __shared__ int s[SCAN_BLK];
    int t = threadIdx.x;
    int i = blockIdx.x * SCAN_BLK + t;
    int v = (i < N_NODES) ? deg[i] : 0;
    s[t] = v;
    __syncthreads();
    for (int off = 1; off < SCAN_BLK; off <<= 1) {
        int u = (t >= off) ? s[t - off] : 0;
        __syncthreads();
        s[t] += u;
        __syncthreads();
    }
    int excl = s[t] - v + block_off[blockIdx.x];
    if (i < N_NODES) {
        row_ptr[i] = excl;
        cursor[i]  = excl;
        deg_inv[i] = 1.0f / (float)max(v, 1);
    }
    if (i == N_NODES) row_ptr[N_NODES] = excl;
}

__global__ void fill_csr(const int* __restrict__ src, const int* __restrict__ dst,
                         int* __restrict__ cursor, int* __restrict__ col) {
    int e = blockIdx.x * blockDim.x + threadIdx.x;
    if (e < N_EDGES) {
        int d = dst[e];
        int pos = atomicAdd(&cursor[d], 1);
        col[pos] = src[e];
    }
}

// ---------------- splits ----------------

__global__ void split_sep(const float* __restrict__ src,
                          _Float16* __restrict__ hi, _Float16* __restrict__ lo, int n4) {
    int i = blockIdx.x * blockDim.x + threadIdx.x;
    if (i >= n4) return;
    float4 v = *(const float4*)(src + (size_t)i * 4);
    half4 h, l;
    h.x = (_Float16)v.x; l.x = (_Float16)(v.x - (float)h.x);
    h.y = (_Float16)v.y; l.y = (_Float16)(v.y - (float)h.y);
    h.z = (_Float16)v.z; l.z = (_Float16)(v.z - (float)h.z);
    h.w = (_Float16)v.w; l.w = (_Float16)(v.w - (float)h.w);
    *(half4*)(hi + (size_t)i * 4) = h;
    *(half4*)(lo + (size_t)i * 4) = l;
}

// features: packed u32, SLICE-MAJOR layout [slice][node][16]
__global__ void split_pk_sl(const float* __restrict__ src, u32* __restrict__ dst, int nq) {
    int i = blockIdx.x * blockDim.x + threadIdx.x;   // quad index
    if (i >= nq) return;
    int n = i >> 5;          // node
    int c = i & 31;          // quad within row (4 features)
    float4 v = *(const float4*)(src + (size_t)n * HID + c * 4);
    uint4 r;
    r.x = pack_split(v.x); r.y = pack_split(v.y);
    r.z = pack_split(v.z); r.w = pack_split(v.w);
    int slice = c >> 2, rem = (c & 3) * 4;
    *(uint4*)(dst + (size_t)slice * SL_STRIDE + (size_t)n * 16 + rem) = r;
}

// ---- slice-major mean aggregation, lane-per-feature (no cross-lane reduce) ----
// 16-lane group owns one (node, slice); lane f accumulates feature f serially
// over the node's edges. col[e] is uniform within the group (HW broadcast).
// slice = blockIdx&7 -> XCD pinning: each XCD's L2 caches one 3.2MB slice.

__global__ __launch_bounds__(512) void aggregate_sl(const u32* __restrict__ hp,
        const int* __restrict__ row_ptr, const int* __restrict__ col,
        const float* __restrict__ deg_inv, u32* __restrict__ mp) {
    const int tid   = threadIdx.x;
    const int g     = tid >> 4;          // 16-lane group: 0..31
    const int f     = tid & 15;          // feature u32 within slice
    const int slice = blockIdx.x & 7;
    const int node  = (blockIdx.x >> 3) * 32 + g;
    if (node >= N_NODES) return;
    const u32* hsl = hp + (size_t)slice * SL_STRIDE;
    const int beg = row_ptr[node], end = row_ptr[node + 1];
    float acc = 0.f;
    int e = beg;
    for (; e + 3 < end; e += 4) {        // 4 independent gathers in flight
        int s0 = col[e], s1 = col[e + 1], s2 = col[e + 2], s3 = col[e + 3];
        u32 v0 = hsl[(size_t)s0 * 16 + f];
        u32 v1 = hsl[(size_t)s1 * 16 + f];
        u32 v2 = hsl[(size_t)s2 * 16 + f];
        u32 v3 = hsl[(size_t)s3 * 16 + f];
        acc += unpack_sum(v0) + unpack_sum(v1) + unpack_sum(v2) + unpack_sum(v3);
    }
    for (; e < end; ++e)
        acc += unpack_sum(hsl[(size_t)col[e] * 16 + f]);
    mp[(size_t)slice * SL_STRIDE + (size_t)node * 16 + f] =
        pack_split(acc * deg_inv[node]);
}

// ---------------- MFMA GEMM, slice-major A, two-phase hi/lo weight staging ------
// 512 thr = 8 waves x 16 rows = 128 rows/block, 391 blocks. LDS 64KB.
// Phase A loads A (packed) once; hi parts kept in registers for phase B
// (saves 51MB/layer of re-reads).

__device__ inline void unpk8(u32x8 p, half8& hi, half8& lo) {
    #pragma unroll
    for (int i = 0; i < 8; ++i) {
        PK t; t.u = p[i];
        hi[i] = t.h[0];
        lo[i] = t.h[1];
    }
}

__global__ __launch_bounds__(512, 3) void gemm_mfma(
        const u32* __restrict__ mean_pk, const u32* __restrict__ h_pk,
        const _Float16* __restrict__ Wlh, const _Float16* __restrict__ Wll,
        const _Float16* __restrict__ Wrh, const _Float16* __restrict__ Wrl,
        const float* __restrict__ bias,
        u32* __restrict__ out_pk, float* __restrict__ out_f32, int final_layer) {
    __shared__ char Wlds[65536];           // 2 mats x [128 j][128 k] fp16, swizzled
    const int t    = threadIdx.x;
    const int lane = t & 63;
    const int w    = t >> 6;
    const int jr   = lane & 15;
    const int q    = lane >> 4;

    const int basew = blockIdx.x * 128 + w * 16;
    int r0 = basew + jr; if (r0 > N_NODES - 1) r0 = N_NODES - 1;

    f32x4 accL[8], accR[8];
    #pragma unroll
    for (int jt = 0; jt < 8; ++jt) { accL[jt] = (f32x4)(0.f); accR[jt] = (f32x4)(0.f); }

    // ---- phase A: hi weights (Wlh, Wrh); cache hi-A in registers ----
    #pragma unroll
    for (int i = 0; i < 4; ++i) {
        int gi = t + i * 512;
        int j = gi >> 4, p = gi & 15;
        int dstb = j * 256 + ((p ^ (j & 7)) * 16);
        int srci = j * HID + p * 8;
        *(half8*)&Wlds[dstb]         = *(const half8*)(Wlh + srci);
        *(half8*)&Wlds[32768 + dstb] = *(const half8*)(Wrh + srci);
    }
    __syncthreads();

    half8 mhs[4], hhs[4];
    #pragma unroll
    for (int kk = 0; kk < 4; ++kk) {
        size_t a = ((size_t)(2 * kk + (q >> 1)) * N_NODES + r0) * 16 + (q & 1) * 8;
        u32x8 mp8 = *(const u32x8*)(mean_pk + a);
        u32x8 hp8 = *(const u32x8*)(h_pk + a);
        half8 mh, ml, hh, hl;
        unpk8(mp8, mh, ml); unpk8(hp8, hh, hl);
        mhs[kk] = mh; hhs[kk] = hh;
        #pragma unroll
        for (int jt = 0; jt < 8; ++jt) {
            int j  = jt * 16 + jr;
            int wb = j * 256 + (((kk * 4 + q) ^ (j & 7)) * 16);
            half8 wl = *(const half8*)&Wlds[wb];
            half8 wr = *(const half8*)&Wlds[32768 + wb];
            accL[jt] = __builtin_amdgcn_mfma_f32_16x16x32_f16(mh, wl, accL[jt], 0, 0, 0);
            accL[jt] = __builtin_amdgcn_mfma_f32_16x16x32_f16(ml, wl, accL[jt], 0, 0, 0);
            accR[jt] = __builtin_amdgcn_mfma_f32_16x16x32_f16(hh, wr, accR[jt], 0, 0, 0);
            accR[jt] = __builtin_amdgcn_mfma_f32_16x16x32_f16(hl, wr, accR[jt], 0, 0, 0);
        }
    }
    __syncthreads();

    // ---- phase B: lo weights (Wll, Wrl); A-hi from registers ----
    #pragma unroll
    for (int i = 0; i < 4; ++i) {
        int gi = t + i * 512;
        int j = gi >> 4, p = gi & 15;
        int dstb = j * 256 + ((p ^ (j & 7)) * 16);
        int srci = j * HID + p * 8;
        *(half8*)&Wlds[dstb]         = *(const half8*)(Wll + srci);
        *(half8*)&Wlds[32768 + dstb] = *(const half8*)(Wrl + srci);
    }
    __syncthreads();
    #pragma unroll
    for (int kk = 0; kk < 4; ++kk) {
        half8 mh = mhs[kk], hh = hhs[kk];
        #pragma unroll
        for (int jt = 0; jt < 8; ++jt) {
            int j  = jt * 16 + jr;
            int wb = j * 256 + (((kk * 4 + q) ^ (j & 7)) * 16);
            half8 wl = *(const half8*)&Wlds[wb];
            half8 wr = *(const half8*)&Wlds[32768 + wb];
            accL[jt] = __builtin_amdgcn_mfma_f32_16x16x32_f16(mh, wl, accL[jt], 0, 0, 0);
            accR[jt] = __builtin_amdgcn_mfma_f32_16x16x32_f16(hh, wr, accR[jt], 0, 0, 0);
        }
    }

    // ---- epilogue: C/D row=(lane>>4)*4+g, col=lane&15 ----
    float bv[8];
    #pragma unroll
    for (int jt = 0; jt < 8; ++jt) bv[jt] = bias[jt * 16 + jr];

    #pragma unroll
    for (int jt = 0; jt < 8; ++jt) {
        #pragma unroll
        for (int g = 0; g < 4; ++g) {
            int row = basew + q * 4 + g;
            if (row < N_NODES) {
                float v = accL[jt][g] + accR[jt][g] + bv[jt];
                if (final_layer) {
                    out_f32[(size_t)row * HID + jt * 16 + jr] = v;
                } else {
                    out_pk[((size_t)jt * N_NODES + row) * 16 + jr] =
                        pack_split(fmaxf(v, 0.f));
                }
            }
        }
    }
}

// ---------------- launch ----------------

extern "C" void kernel_launch(void* const* d_in, const int* in_sizes, int n_in,
                              void* d_out, int out_size, void* d_ws, size_t ws_size,
                              hipStream_t stream) {
    const float* x    = (const float*)d_in[0];
    const int*   edge = (const int*)d_in[1];
    const float* Wl   = (const float*)d_in[2];
    const float* Wr   = (const float*)d_in[3];
    const float* bias = (const float*)d_in[4];
    float* out = (float*)d_out;

    u32* h_pk    = (u32*)d_ws;                    // 25.6 MB, slice-major
    u32* mean_pk = h_pk + NH;                     // 25.6 MB, slice-major
    _Float16* Wlh = (_Float16*)(mean_pk + NH);
    _Float16* Wll = Wlh + 81920;
    _Float16* Wrh = Wll + 81920;
    _Float16* Wrl = Wrh + 81920;
    float* deg_inv = (float*)(Wrl + 81920);
    int*   deg     = (int*)(deg_inv + N_NODES);
    int*   row_ptr = deg + N_NODES;
    int*   cursor  = row_ptr + (N_NODES + 1);
    int*   colarr  = cursor + N_NODES;
    int*   blk_sums = colarr + N_EDGES;
    int*   blk_off  = blk_sums + N_SCAN_BLOCKS;

    const int* src = edge;
    const int* dst = edge + N_EDGES;

    hipMemsetAsync(deg, 0, N_NODES * sizeof(int), stream);
    deg_count<<<(N_EDGES + 255) / 256, 256, 0, stream>>>(dst, deg);
    deg_reduce<<<N_SCAN_BLOCKS, SCAN_BLK, 0, stream>>>(deg, blk_sums);
    scan_partials<<<1, SCAN_BLK, 0, stream>>>(blk_sums, blk_off);
    scan_write<<<N_SCAN_BLOCKS, SCAN_BLK, 0, stream>>>(deg, blk_off, row_ptr,
                                                       cursor, deg_inv);
    fill_csr<<<(N_EDGES + 255) / 256, 256, 0, stream>>>(src, dst, cursor, colarr);

    split_sep<<<(20480 + 255) / 256, 256, 0, stream>>>(Wl, Wlh, Wll, 20480);
    split_sep<<<(20480 + 255) / 256, 256, 0, stream>>>(Wr, Wrh, Wrl, 20480);
    split_pk_sl<<<(1600000 + 255) / 256, 256, 0, stream>>>(x, h_pk, 1600000);

    const int agg_blocks = ((N_NODES + 31) / 32) * NSLICE;   // 12504
    const int gemm_blocks = (N_NODES + 127) / 128;           // 391

    for (int l = 0; l < N_LAYERS; ++l) {
        aggregate_sl<<<agg_blocks, 512, 0, stream>>>(
            h_pk, row_ptr, colarr, deg_inv, mean_pk);
        gemm_mfma<<<gemm_blocks, 512, 0, stream>>>(
            mean_pk, h_pk,
            Wlh + (size_t)l * 16384, Wll + (size_t)l * 16384,
            Wrh + (size_t)l * 16384, Wrl + (size_t)l * 16384,
            bias + (size_t)l * HID,
            h_pk, out, (l == N_LAYERS - 1) ? 1 : 0);
    }
}

// Round 8
// 407.671 us; speedup vs baseline: 1.7381x; 1.3111x over previous
//
#include <hip/hip_runtime.h>

#define N_NODES 50000
#define N_EDGES 600000
#define HID 128
#define N_LAYERS 5
#define SCAN_BLK 256
#define N_SCAN_BLOCKS ((N_NODES + SCAN_BLK - 1) / SCAN_BLK)   // 196
#define NH ((size_t)N_NODES * HID)
#define NSLICE 8
#define SL_STRIDE ((size_t)N_NODES * 16)   // u32 per slice

typedef unsigned int u32;
typedef _Float16 half8 __attribute__((ext_vector_type(8)));
typedef _Float16 half4 __attribute__((ext_vector_type(4)));
typedef float f32x4 __attribute__((ext_vector_type(4)));
typedef u32 u32x8 __attribute__((ext_vector_type(8)));

// packed split format: one u32 per feature; h[0]=fp16 hi, h[1]=fp16 residual
union PK { u32 u; _Float16 h[2]; };

__device__ inline u32 pack_split(float v) {
    PK r;
    r.h[0] = (_Float16)v;
    r.h[1] = (_Float16)(v - (float)r.h[0]);
    return r.u;
}
__device__ inline float unpack_sum(u32 p) {
    PK r; r.u = p;
    return (float)r.h[0] + (float)r.h[1];
}

// ---------------- CSR build ----------------

__global__ void deg_count(const int* __restrict__ dst, int* __restrict__ deg) {
    int e = blockIdx.x * blockDim.x + threadIdx.x;
    if (e < N_EDGES) atomicAdd(&deg[dst[e]], 1);
}

__global__ __launch_bounds__(SCAN_BLK) void deg_reduce(const int* __restrict__ deg,
                                                       int* __restrict__ block_sums) {
    __shared__ int s[SCAN_BLK];
    int i = blockIdx.x * SCAN_BLK + threadIdx.x;
    int v = (i < N_NODES) ? deg[i] : 0;
    s[threadIdx.x] = v;
    __syncthreads();
    for (int off = SCAN_BLK / 2; off > 0; off >>= 1) {
        if (threadIdx.x < off) s[threadIdx.x] += s[threadIdx.x + off];
        __syncthreads();
    }
    if (threadIdx.x == 0) block_sums[blockIdx.x] = s[0];
}

__global__ __launch_bounds__(SCAN_BLK) void scan_partials(const int* __restrict__ block_sums,
                                                          int* __restrict__ block_off) {
    __shared__ int s[SCAN_BLK];
    int t = threadIdx.x;
    int v = (t < N_SCAN_BLOCKS) ? block_sums[t] : 0;
    s[t] = v;
    __syncthreads();
    for (int off = 1; off < SCAN_BLK; off <<= 1) {
        int u = (t >= off) ? s[t - off] : 0;
        __syncthreads();
        s[t] += u;
        __syncthreads();
    }
    if (t < N_SCAN_BLOCKS) block_off[t] = s[t] - v;
}

__global__ __launch_bounds__(SCAN_BLK) void scan_write(const int* __restrict__ deg,
        const int* __restrict__ block_off, int* __restrict__ row_ptr,
        int* __restrict__ cursor, float* __restrict__ deg_inv) {
    __shared__ int s[SCAN_BLK];
    int t = threadIdx.x;
    int i = blockIdx.x * SCAN_BLK + t;
    int v = (i < N_NODES) ? deg[i] : 0;
    s[t] = v;
    __syncthreads();
    for (int off = 1; off < SCAN_BLK; off <<= 1) {
        int u = (t >= off) ? s[t - off] : 0;
        __syncthreads();
        s[t] += u;
        __syncthreads();
    }
    int excl = s[t] - v + block_off[blockIdx.x];
    if (i < N_NODES) {
        row_ptr[i] = excl;
        cursor[i]  = excl;
        deg_inv[i] = 1.0f / (float)max(v, 1);
    }
    if (i == N_NODES) row_ptr[N_NODES] = excl;
}

__global__ void fill_csr(const int* __restrict__ src, const int* __restrict__ dst,
                         int* __restrict__ cursor, int* __restrict__ col) {
    int e = blockIdx.x * blockDim.x + threadIdx.x;
    if (e < N_EDGES) {
        int d = dst[e];
        int pos = atomicAdd(&cursor[d], 1);
        col[pos] = src[e];
    }
}

// ---------------- splits ----------------

__global__ void split_sep(const float* __restrict__ src,
                          _Float16* __restrict__ hi, _Float16* __restrict__ lo, int n4) {
    int i = blockIdx.x * blockDim.x + threadIdx.x;
    if (i >= n4) return;
    float4 v = *(const float4*)(src + (size_t)i * 4);
    half4 h, l;
    h.x = (_Float16)v.x; l.x = (_Float16)(v.x - (float)h.x);
    h.y = (_Float16)v.y; l.y = (_Float16)(v.y - (float)h.y);
    h.z = (_Float16)v.z; l.z = (_Float16)(v.z - (float)h.z);
    h.w = (_Float16)v.w; l.w = (_Float16)(v.w - (float)h.w);
    *(half4*)(hi + (size_t)i * 4) = h;
    *(half4*)(lo + (size_t)i * 4) = l;
}

// features: packed u32, SLICE-MAJOR layout [slice][node][16]
__global__ void split_pk_sl(const float* __restrict__ src, u32* __restrict__ dst, int nq) {
    int i = blockIdx.x * blockDim.x + threadIdx.x;   // quad index
    if (i >= nq) return;
    int n = i >> 5;          // node
    int c = i & 31;          // quad within row (4 features)
    float4 v = *(const float4*)(src + (size_t)n * HID + c * 4);
    uint4 r;
    r.x = pack_split(v.x); r.y = pack_split(v.y);
    r.z = pack_split(v.z); r.w = pack_split(v.w);
    int slice = c >> 2, rem = (c & 3) * 4;
    *(uint4*)(dst + (size_t)slice * SL_STRIDE + (size_t)n * 16 + rem) = r;
}

// ---- slice-major mean aggregation: 4-lane group per (node,slice) ----
// Lane q of a group owns u32s [4q,4q+4) of the 64B slice-row and accumulates
// them serially over the node's edges (uint4 loads, no cross-lane reduce,
// no shuffles). Feature row-slice = exactly one 64B cache line per edge.
// slice = blockIdx&7 -> XCD pinning: each XCD's L2 caches one 3.2MB slice.

__global__ __launch_bounds__(256) void aggregate_g4(const u32* __restrict__ hp,
        const int* __restrict__ row_ptr, const int* __restrict__ col,
        const float* __restrict__ deg_inv, u32* __restrict__ mp) {
    const int wave  = threadIdx.x >> 6;
    const int lane  = threadIdx.x & 63;
    const int grp   = lane >> 2;          // 16 node-groups per wave
    const int q4    = (lane & 3) * 4;     // u32 offset of this lane's quad
    const int slice = blockIdx.x & 7;
    const int node  = (blockIdx.x >> 3) * 64 + wave * 16 + grp;
    if (node >= N_NODES) return;
    const u32* hsl = hp + (size_t)slice * SL_STRIDE + q4;
    const int beg = row_ptr[node], end = row_ptr[node + 1];
    float a0 = 0.f, a1 = 0.f, a2 = 0.f, a3 = 0.f;
    int e = beg;
    for (; e + 3 < end; e += 4) {         // 4 row-lines in flight per group
        int s0 = col[e], s1 = col[e + 1], s2 = col[e + 2], s3 = col[e + 3];
        uint4 v0 = *(const uint4*)(hsl + (unsigned)s0 * 16u);
        uint4 v1 = *(const uint4*)(hsl + (unsigned)s1 * 16u);
        uint4 v2 = *(const uint4*)(hsl + (unsigned)s2 * 16u);
        uint4 v3 = *(const uint4*)(hsl + (unsigned)s3 * 16u);
        a0 += unpack_sum(v0.x) + unpack_sum(v1.x) + unpack_sum(v2.x) + unpack_sum(v3.x);
        a1 += unpack_sum(v0.y) + unpack_sum(v1.y) + unpack_sum(v2.y) + unpack_sum(v3.y);
        a2 += unpack_sum(v0.z) + unpack_sum(v1.z) + unpack_sum(v2.z) + unpack_sum(v3.z);
        a3 += unpack_sum(v0.w) + unpack_sum(v1.w) + unpack_sum(v2.w) + unpack_sum(v3.w);
    }
    for (; e < end; ++e) {
        uint4 v0 = *(const uint4*)(hsl + (unsigned)col[e] * 16u);
        a0 += unpack_sum(v0.x); a1 += unpack_sum(v0.y);
        a2 += unpack_sum(v0.z); a3 += unpack_sum(v0.w);
    }
    const float di = deg_inv[node];
    uint4 r;
    r.x = pack_split(a0 * di);
    r.y = pack_split(a1 * di);
    r.z = pack_split(a2 * di);
    r.w = pack_split(a3 * di);
    *(uint4*)(mp + (size_t)slice * SL_STRIDE + (size_t)node * 16 + q4) = r;
}

// ---------------- MFMA GEMM, slice-major A, two-phase hi/lo weight staging ------
// 512 thr = 8 waves x 16 rows = 128 rows/block, 391 blocks. LDS 64KB.
// Phase A loads A (packed) once; hi parts kept in registers for phase B.

__device__ inline void unpk8(u32x8 p, half8& hi, half8& lo) {
    #pragma unroll
    for (int i = 0; i < 8; ++i) {
        PK t; t.u = p[i];
        hi[i] = t.h[0];
        lo[i] = t.h[1];
    }
}

__global__ __launch_bounds__(512, 3) void gemm_mfma(
        const u32* __restrict__ mean_pk, const u32* __restrict__ h_pk,
        const _Float16* __restrict__ Wlh, const _Float16* __restrict__ Wll,
        const _Float16* __restrict__ Wrh, const _Float16* __restrict__ Wrl,
        const float* __restrict__ bias,
        u32* __restrict__ out_pk, float* __restrict__ out_f32, int final_layer) {
    __shared__ char Wlds[65536];           // 2 mats x [128 j][128 k] fp16, swizzled
    const int t    = threadIdx.x;
    const int lane = t & 63;
    const int w    = t >> 6;
    const int jr   = lane & 15;
    const int q    = lane >> 4;

    const int basew = blockIdx.x * 128 + w * 16;
    int r0 = basew + jr; if (r0 > N_NODES - 1) r0 = N_NODES - 1;

    f32x4 accL[8], accR[8];
    #pragma unroll
    for (int jt = 0; jt < 8; ++jt) { accL[jt] = (f32x4)(0.f); accR[jt] = (f32x4)(0.f); }

    // ---- phase A: hi weights (Wlh, Wrh); cache hi-A in registers ----
    #pragma unroll
    for (int i = 0; i < 4; ++i) {
        int gi = t + i * 512;
        int j = gi >> 4, p = gi & 15;
        int dstb = j * 256 + ((p ^ (j & 7)) * 16);
        int srci = j * HID + p * 8;
        *(half8*)&Wlds[dstb]         = *(const half8*)(Wlh + srci);
        *(half8*)&Wlds[32768 + dstb] = *(const half8*)(Wrh + srci);
    }
    __syncthreads();

    half8 mhs[4], hhs[4];
    #pragma unroll
    for (int kk = 0; kk < 4; ++kk) {
        size_t a = ((size_t)(2 * kk + (q >> 1)) * N_NODES + r0) * 16 + (q & 1) * 8;
        u32x8 mp8 = *(const u32x8*)(mean_pk + a);
        u32x8 hp8 = *(const u32x8*)(h_pk + a);
        half8 mh, ml, hh, hl;
        unpk8(mp8, mh, ml); unpk8(hp8, hh, hl);
        mhs[kk] = mh; hhs[kk] = hh;
        #pragma unroll
        for (int jt = 0; jt < 8; ++jt) {
            int j  = jt * 16 + jr;
            int wb = j * 256 + (((kk * 4 + q) ^ (j & 7)) * 16);
            half8 wl = *(const half8*)&Wlds[wb];
            half8 wr = *(const half8*)&Wlds[32768 + wb];
            accL[jt] = __builtin_amdgcn_mfma_f32_16x16x32_f16(mh, wl, accL[jt], 0, 0, 0);
            accL[jt] = __builtin_amdgcn_mfma_f32_16x16x32_f16(ml, wl, accL[jt], 0, 0, 0);
            accR[jt] = __builtin_amdgcn_mfma_f32_16x16x32_f16(hh, wr, accR[jt], 0, 0, 0);
            accR[jt] = __builtin_amdgcn_mfma_f32_16x16x32_f16(hl, wr, accR[jt], 0, 0, 0);
        }
    }
    __syncthreads();

    // ---- phase B: lo weights (Wll, Wrl); A-hi from registers ----
    #pragma unroll
    for (int i = 0; i < 4; ++i) {
        int gi = t + i * 512;
        int j = gi >> 4, p = gi & 15;
        int dstb = j * 256 + ((p ^ (j & 7)) * 16);
        int srci = j * HID + p * 8;
        *(half8*)&Wlds[dstb]         = *(const half8*)(Wll + srci);
        *(half8*)&Wlds[32768 + dstb] = *(const half8*)(Wrl + srci);
    }
    __syncthreads();
    #pragma unroll
    for (int kk = 0; kk < 4; ++kk) {
        half8 mh = mhs[kk], hh = hhs[kk];
        #pragma unroll
        for (int jt = 0; jt < 8; ++jt) {
            int j  = jt * 16 + jr;
            int wb = j * 256 + (((kk * 4 + q) ^ (j & 7)) * 16);
            half8 wl = *(const half8*)&Wlds[wb];
            half8 wr = *(const half8*)&Wlds[32768 + wb];
            accL[jt] = __builtin_amdgcn_mfma_f32_16x16x32_f16(mh, wl, accL[jt], 0, 0, 0);
            accR[jt] = __builtin_amdgcn_mfma_f32_16x16x32_f16(hh, wr, accR[jt], 0, 0, 0);
        }
    }

    // ---- epilogue: C/D row=(lane>>4)*4+g, col=lane&15 ----
    float bv[8];
    #pragma unroll
    for (int jt = 0; jt < 8; ++jt) bv[jt] = bias[jt * 16 + jr];

    #pragma unroll
    for (int jt = 0; jt < 8; ++jt) {
        #pragma unroll
        for (int g = 0; g < 4; ++g) {
            int row = basew + q * 4 + g;
            if (row < N_NODES) {
                float v = accL[jt][g] + accR[jt][g] + bv[jt];
                if (final_layer) {
                    out_f32[(size_t)row * HID + jt * 16 + jr] = v;
                } else {
                    out_pk[((size_t)jt * N_NODES + row) * 16 + jr] =
                        pack_split(fmaxf(v, 0.f));
                }
            }
        }
    }
}

// ---------------- launch ----------------

extern "C" void kernel_launch(void* const* d_in, const int* in_sizes, int n_in,
                              void* d_out, int out_size, void* d_ws, size_t ws_size,
                              hipStream_t stream) {
    const float* x    = (const float*)d_in[0];
    const int*   edge = (const int*)d_in[1];
    const float* Wl   = (const float*)d_in[2];
    const float* Wr   = (const float*)d_in[3];
    const float* bias = (const float*)d_in[4];
    float* out = (float*)d_out;

    u32* h_pk    = (u32*)d_ws;                    // 25.6 MB, slice-major
    u32* mean_pk = h_pk + NH;                     // 25.6 MB, slice-major
    _Float16* Wlh = (_Float16*)(mean_pk + NH);
    _Float16* Wll = Wlh + 81920;
    _Float16* Wrh = Wll + 81920;
    _Float16* Wrl = Wrh + 81920;
    float* deg_inv = (float*)(Wrl + 81920);
    int*   deg     = (int*)(deg_inv + N_NODES);
    int*   row_ptr = deg + N_NODES;
    int*   cursor  = row_ptr + (N_NODES + 1);
    int*   colarr  = cursor + N_NODES;
    int*   blk_sums = colarr + N_EDGES;
    int*   blk_off  = blk_sums + N_SCAN_BLOCKS;

    const int* src = edge;
    const int* dst = edge + N_EDGES;

    hipMemsetAsync(deg, 0, N_NODES * sizeof(int), stream);
    deg_count<<<(N_EDGES + 255) / 256, 256, 0, stream>>>(dst, deg);
    deg_reduce<<<N_SCAN_BLOCKS, SCAN_BLK, 0, stream>>>(deg, blk_sums);
    scan_partials<<<1, SCAN_BLK, 0, stream>>>(blk_sums, blk_off);
    scan_write<<<N_SCAN_BLOCKS, SCAN_BLK, 0, stream>>>(deg, blk_off, row_ptr,
                                                       cursor, deg_inv);
    fill_csr<<<(N_EDGES + 255) / 256, 256, 0, stream>>>(src, dst, cursor, colarr);

    split_sep<<<(20480 + 255) / 256, 256, 0, stream>>>(Wl, Wlh, Wll, 20480);
    split_sep<<<(20480 + 255) / 256, 256, 0, stream>>>(Wr, Wrh, Wrl, 20480);
    split_pk_sl<<<(1600000 + 255) / 256, 256, 0, stream>>>(x, h_pk, 1600000);

    const int agg_blocks = ((N_NODES + 63) / 64) * NSLICE;   // 6256
    const int gemm_blocks = (N_NODES + 127) / 128;           // 391

    for (int l = 0; l < N_LAYERS; ++l) {
        aggregate_g4<<<agg_blocks, 256, 0, stream>>>(
            h_pk, row_ptr, colarr, deg_inv, mean_pk);
        gemm_mfma<<<gemm_blocks, 512, 0, stream>>>(
            mean_pk, h_pk,
            Wlh + (size_t)l * 16384, Wll + (size_t)l * 16384,
            Wrh + (size_t)l * 16384, Wrl + (size_t)l * 16384,
            bias + (size_t)l * HID,
            h_pk, out, (l == N_LAYERS - 1) ? 1 : 0);
    }
}